// Round 2
// baseline (299.099 us; speedup 1.0000x reference)
//
#include <hip/hip_runtime.h>
#include <math.h>

// Problem constants (from reference): B=64, J=17, H=W=96 -> HW=9216, TOPK=8
#define NB 64
#define NJ 17
#define HW 9216
#define NBJ (NB * NJ)              // 1088
#define TOPK_K 8
#define NSEG 3
#define SEG_F4 (HW / 4 / NSEG)     // 768 float4 per segment
#define BLK 256                    // threads per block (4 waves)
#define F4_PER_THR (SEG_F4 / BLK)  // 3 float4 per tensor per thread
#define NBLOCKS (NBJ * NSEG)       // 3264 blocks (12.75/CU -> ~2% tail)
#define WS_OFF 4                   // floats: counter occupies ws[0..3] (16 B)

// Single fused kernel. Streaming phase identical to the proven pass1
// (perfectly coalesced float4, 9 loads in flight/thread, w^2 factored out
// algebraically). Then last-block election: the final-arriving block folds
// segments, applies w^2, computes cond/mse/topk — removing the second
// dispatch and its launch gap entirely.
__global__ __launch_bounds__(BLK) void fused_kernel(
    const float* __restrict__ s,
    const float* __restrict__ t,
    const float* __restrict__ g,
    const float* __restrict__ w,
    const int* __restrict__ enj_p,
    float* __restrict__ out,
    float* __restrict__ ws_raw)
{
    unsigned int* cnt = (unsigned int*)ws_raw;   // zeroed by hipMemsetAsync
    float* ws = ws_raw + WS_OFF;                 // [metric][seg][bj]

    const int bj  = blockIdx.x / NSEG;
    const int seg = blockIdx.x % NSEG;
    const size_t base4 = (size_t)bj * (HW / 4) + (size_t)seg * SEG_F4;
    const float4* __restrict__ s4 = (const float4*)s + base4;
    const float4* __restrict__ t4 = (const float4*)t + base4;
    const float4* __restrict__ g4 = (const float4*)g + base4;

    float4 a[F4_PER_THR], b[F4_PER_THR], c[F4_PER_THR];
    #pragma unroll
    for (int k = 0; k < F4_PER_THR; ++k) a[k] = s4[threadIdx.x + k * BLK];
    #pragma unroll
    for (int k = 0; k < F4_PER_THR; ++k) b[k] = t4[threadIdx.x + k * BLK];
    #pragma unroll
    for (int k = 0; k < F4_PER_THR; ++k) c[k] = g4[threadIdx.x + k * BLK];

    float ssg = 0.f, sst = 0.f, mg = -INFINITY;

    #define ACCUM(av, bv, cv)                                \
        {                                                    \
            float d1 = (av) - (cv), d2 = (av) - (bv);        \
            ssg += d1 * d1; sst += d2 * d2;                  \
            mg = fmaxf(mg, (cv));                            \
        }

    #pragma unroll
    for (int k = 0; k < F4_PER_THR; ++k) {
        ACCUM(a[k].x, b[k].x, c[k].x)
        ACCUM(a[k].y, b[k].y, c[k].y)
        ACCUM(a[k].z, b[k].z, c[k].z)
        ACCUM(a[k].w, b[k].w, c[k].w)
    }
    #undef ACCUM

    // wave64 butterfly reduction
    #pragma unroll
    for (int off = 32; off > 0; off >>= 1) {
        ssg += __shfl_down(ssg, off);
        sst += __shfl_down(sst, off);
        mg = fmaxf(mg, __shfl_down(mg, off));
    }

    __shared__ float sh_sg[4], sh_st[4], sh_mg4[4];
    const int wave = threadIdx.x >> 6;
    const int lane = threadIdx.x & 63;
    if (lane == 0) { sh_sg[wave] = ssg; sh_st[wave] = sst; sh_mg4[wave] = mg; }
    __syncthreads();
    if (threadIdx.x == 0) {
        const float fsg = (sh_sg[0] + sh_sg[1]) + (sh_sg[2] + sh_sg[3]);
        const float fst = (sh_st[0] + sh_st[1]) + (sh_st[2] + sh_st[3]);
        const float fmg = fmaxf(fmaxf(sh_mg4[0], sh_mg4[1]),
                                fmaxf(sh_mg4[2], sh_mg4[3]));
        ws[(0 * NSEG + seg) * NBJ + bj] = fsg;
        ws[(1 * NSEG + seg) * NBJ + bj] = fst;
        ws[(2 * NSEG + seg) * NBJ + bj] = fmg;
    }

    // ---- last-block election (release: fence before device-scope atomic) ----
    __shared__ int is_last;
    if (threadIdx.x == 0) {
        __threadfence();
        const unsigned old = atomicAdd(cnt, 1u);
        is_last = (old == (unsigned)(NBLOCKS - 1)) ? 1 : 0;
    }
    __syncthreads();
    if (!is_last) return;
    __threadfence();  // acquire: all blocks' ws writes now visible

    // ---- final phase: one block, 256 threads ----
    __shared__ float sh_ssg[NBJ];
    __shared__ float sh_sst[NBJ];
    __shared__ float sh_mgA[NBJ];
    __shared__ float cond_sh[NJ];
    __shared__ float msum_sh[NJ];
    const int tid = threadIdx.x;

    // Stage 1: fold segments, scale by w^2; coalesced in bj.
    for (int i = tid; i < NBJ; i += BLK) {
        float fsg = 0.f, fst = 0.f, fmg = -INFINITY;
        #pragma unroll
        for (int sg2 = 0; sg2 < NSEG; ++sg2) {
            fsg += ws[(0 * NSEG + sg2) * NBJ + i];
            fst += ws[(1 * NSEG + sg2) * NBJ + i];
            fmg = fmaxf(fmg, ws[(2 * NSEG + sg2) * NBJ + i]);
        }
        const float wv = w[i];
        const float w2 = wv * wv;
        sh_ssg[i] = fsg * w2;
        sh_sst[i] = fst * w2;
        sh_mgA[i] = fmg;
    }
    __syncthreads();

    // Stage 2: per-joint cond + mse. 8 lanes per joint (17*8 = 136 threads),
    // each folds 8 of 64 batch entries, then an intra-8-lane shuffle tree.
    // Groups of 8 are lane-aligned within wave64.
    if (tid < NJ * 8) {
        const int j = tid >> 3;
        const int sub = tid & 7;
        float fsg = 0.f, fst = 0.f, fmg = -INFINITY;
        for (int bb = sub; bb < NB; bb += 8) {
            fsg += sh_ssg[bb * NJ + j];
            fst += sh_sst[bb * NJ + j];
            fmg = fmaxf(fmg, sh_mgA[bb * NJ + j]);
        }
        #pragma unroll
        for (int off = 4; off > 0; off >>= 1) {
            fsg += __shfl_down(fsg, off);
            fst += __shfl_down(fst, off);
            fmg = fmaxf(fmg, __shfl_down(fmg, off));
        }
        if (sub == 0) {
            const bool cond = (fmg == 1.0f);
            cond_sh[j] = cond ? 1.f : 0.f;
            const float inv_bhw = 1.f / (float)(NB * HW);
            msum_sh[j] = cond ? (fsg * inv_bhw) : ((fsg + fst) * inv_bhw);
        }
    }
    __syncthreads();

    // Stage 3: per-sample top-k on wave 0 (one thread per b), LDS-resident.
    if (tid < NB) {
        float lm[NJ];
        const float inv_hw = 1.f / (float)HW;
        #pragma unroll
        for (int j = 0; j < NJ; ++j) {
            const float fsg = sh_ssg[tid * NJ + j];
            const float fst = sh_sst[tid * NJ + j];
            const float v = (cond_sh[j] != 0.f) ? fsg : (fsg + fst);
            lm[j] = 0.5f * v * inv_hw;
        }
        float tk = 0.f;
        for (int k = 0; k < TOPK_K; ++k) {
            int mi = 0;
            float mv = lm[0];
            #pragma unroll
            for (int j = 1; j < NJ; ++j) {
                if (lm[j] > mv) { mv = lm[j]; mi = j; }
            }
            tk += mv;
            #pragma unroll
            for (int j = 0; j < NJ; ++j) {
                if (j == mi) lm[j] = -INFINITY;
            }
        }
        #pragma unroll
        for (int off = 32; off > 0; off >>= 1) tk += __shfl_down(tk, off);

        if (tid == 0) {
            const float ohkm = tk / (float)(TOPK_K * NB);
            float mse = 0.f;
            for (int j = 0; j < NJ; ++j) mse += msum_sh[j];
            const float enj = (float)(*enj_p);
            out[0] = ohkm;
            out[1] = mse / enj;
            out[2] = ohkm + mse;
        }
    }
}

extern "C" void kernel_launch(void* const* d_in, const int* in_sizes, int n_in,
                              void* d_out, int out_size, void* d_ws, size_t ws_size,
                              hipStream_t stream) {
    const float* output_s = (const float*)d_in[0];
    const float* output_t = (const float*)d_in[1];
    const float* target   = (const float*)d_in[2];
    const float* tweight  = (const float*)d_in[3];
    const int*   enj      = (const int*)d_in[4];
    float* out = (float*)d_out;
    float* ws  = (float*)d_ws;  // [counter(16B)] + 3 * NSEG * NBJ floats

    // zero only the 4-byte last-block counter (workspace is poisoned each run)
    hipMemsetAsync(d_ws, 0, 4, stream);
    fused_kernel<<<NBLOCKS, BLK, 0, stream>>>(output_s, output_t, target,
                                              tweight, enj, out, ws);
}

// Round 3
// 161.903 us; speedup vs baseline: 1.8474x; 1.8474x over previous
//
#include <hip/hip_runtime.h>
#include <math.h>

// Problem constants (from reference): B=64, J=17, H=W=96 -> HW=9216, TOPK=8
#define NB 64
#define NJ 17
#define HW 9216
#define NBJ (NB * NJ)              // 1088
#define TOPK_K 8
#define NSEG 3
#define SEG_F4 (HW / 4 / NSEG)     // 768 float4 per segment
#define BLK 256                    // threads per block (4 waves)
#define F4_PER_THR (SEG_F4 / BLK)  // 3 float4 per tensor per thread
#define NBLOCKS (NBJ * NSEG)       // 3264 blocks
#define WS_OFF 4                   // floats: counter occupies ws[0..3] (16 B)

// Single fused kernel, fence-FREE cross-block handoff.
// Round-2 lesson: __threadfence() on gfx950 = buffer_wbl2 + buffer_inv per
// block (per-XCD L2s are non-coherent) -> L2 thrash, 10x regression.
// Instead: partial sums are published with agent-scope relaxed atomic STOREs
// (sc1 -> write through to Infinity Cache, coherent die-wide), ordered by a
// bare s_waitcnt vmcnt(0), then a RELAXED agent-scope counter RMW. The last
// block reads slots with agent-scope relaxed loads (sc1, bypasses stale L2).
// No cache-maintenance instructions anywhere in the hot path.
__global__ __launch_bounds__(BLK) void fused_kernel(
    const float* __restrict__ s,
    const float* __restrict__ t,
    const float* __restrict__ g,
    const float* __restrict__ w,
    const int* __restrict__ enj_p,
    float* __restrict__ out,
    float* __restrict__ ws_raw)
{
    unsigned int* cnt = (unsigned int*)ws_raw;   // zeroed by hipMemsetAsync
    float* ws = ws_raw + WS_OFF;                 // [metric][seg][bj]

    const int bj  = blockIdx.x / NSEG;
    const int seg = blockIdx.x % NSEG;
    const size_t base4 = (size_t)bj * (HW / 4) + (size_t)seg * SEG_F4;
    const float4* __restrict__ s4 = (const float4*)s + base4;
    const float4* __restrict__ t4 = (const float4*)t + base4;
    const float4* __restrict__ g4 = (const float4*)g + base4;

    float4 a[F4_PER_THR], b[F4_PER_THR], c[F4_PER_THR];
    #pragma unroll
    for (int k = 0; k < F4_PER_THR; ++k) a[k] = s4[threadIdx.x + k * BLK];
    #pragma unroll
    for (int k = 0; k < F4_PER_THR; ++k) b[k] = t4[threadIdx.x + k * BLK];
    #pragma unroll
    for (int k = 0; k < F4_PER_THR; ++k) c[k] = g4[threadIdx.x + k * BLK];

    float ssg = 0.f, sst = 0.f, mg = -INFINITY;

    #define ACCUM(av, bv, cv)                                \
        {                                                    \
            float d1 = (av) - (cv), d2 = (av) - (bv);        \
            ssg += d1 * d1; sst += d2 * d2;                  \
            mg = fmaxf(mg, (cv));                            \
        }

    #pragma unroll
    for (int k = 0; k < F4_PER_THR; ++k) {
        ACCUM(a[k].x, b[k].x, c[k].x)
        ACCUM(a[k].y, b[k].y, c[k].y)
        ACCUM(a[k].z, b[k].z, c[k].z)
        ACCUM(a[k].w, b[k].w, c[k].w)
    }
    #undef ACCUM

    // wave64 butterfly reduction
    #pragma unroll
    for (int off = 32; off > 0; off >>= 1) {
        ssg += __shfl_down(ssg, off);
        sst += __shfl_down(sst, off);
        mg = fmaxf(mg, __shfl_down(mg, off));
    }

    __shared__ float sh_sg[4], sh_st[4], sh_mg4[4];
    const int wave = threadIdx.x >> 6;
    const int lane = threadIdx.x & 63;
    if (lane == 0) { sh_sg[wave] = ssg; sh_st[wave] = sst; sh_mg4[wave] = mg; }
    __syncthreads();

    __shared__ int is_last;
    if (threadIdx.x == 0) {
        const float fsg = (sh_sg[0] + sh_sg[1]) + (sh_sg[2] + sh_sg[3]);
        const float fst = (sh_st[0] + sh_st[1]) + (sh_st[2] + sh_st[3]);
        const float fmg = fmaxf(fmaxf(sh_mg4[0], sh_mg4[1]),
                                fmaxf(sh_mg4[2], sh_mg4[3]));
        // publish partials at agent scope (sc1 -> Infinity Cache, no fence)
        __hip_atomic_store(&ws[(0 * NSEG + seg) * NBJ + bj], fsg,
                           __ATOMIC_RELAXED, __HIP_MEMORY_SCOPE_AGENT);
        __hip_atomic_store(&ws[(1 * NSEG + seg) * NBJ + bj], fst,
                           __ATOMIC_RELAXED, __HIP_MEMORY_SCOPE_AGENT);
        __hip_atomic_store(&ws[(2 * NSEG + seg) * NBJ + bj], fmg,
                           __ATOMIC_RELAXED, __HIP_MEMORY_SCOPE_AGENT);
        // order: stores complete at coherence point before counter bump
        asm volatile("s_waitcnt vmcnt(0)" ::: "memory");
        const unsigned old = __hip_atomic_fetch_add(
            cnt, 1u, __ATOMIC_RELAXED, __HIP_MEMORY_SCOPE_AGENT);
        is_last = (old == (unsigned)(NBLOCKS - 1)) ? 1 : 0;
    }
    __syncthreads();
    if (!is_last) return;

    // ---- final phase: one block, 256 threads ----
    __shared__ float sh_ssg[NBJ];
    __shared__ float sh_sst[NBJ];
    __shared__ float sh_mgA[NBJ];
    __shared__ float cond_sh[NJ];
    __shared__ float msum_sh[NJ];
    const int tid = threadIdx.x;

    // Stage 1: fold segments (agent-scope loads: fresh from IC), apply w^2.
    for (int i = tid; i < NBJ; i += BLK) {
        float fsg = 0.f, fst = 0.f, fmg = -INFINITY;
        #pragma unroll
        for (int sg2 = 0; sg2 < NSEG; ++sg2) {
            fsg += __hip_atomic_load(&ws[(0 * NSEG + sg2) * NBJ + i],
                                     __ATOMIC_RELAXED, __HIP_MEMORY_SCOPE_AGENT);
            fst += __hip_atomic_load(&ws[(1 * NSEG + sg2) * NBJ + i],
                                     __ATOMIC_RELAXED, __HIP_MEMORY_SCOPE_AGENT);
            fmg = fmaxf(fmg,
                  __hip_atomic_load(&ws[(2 * NSEG + sg2) * NBJ + i],
                                     __ATOMIC_RELAXED, __HIP_MEMORY_SCOPE_AGENT));
        }
        const float wv = w[i];
        const float w2 = wv * wv;
        sh_ssg[i] = fsg * w2;
        sh_sst[i] = fst * w2;
        sh_mgA[i] = fmg;
    }
    __syncthreads();

    // Stage 2: per-joint cond + mse. 8 lanes per joint (17*8 = 136 threads),
    // intra-8-lane shuffle tree (groups lane-aligned within wave64).
    if (tid < NJ * 8) {
        const int j = tid >> 3;
        const int sub = tid & 7;
        float fsg = 0.f, fst = 0.f, fmg = -INFINITY;
        for (int bb = sub; bb < NB; bb += 8) {
            fsg += sh_ssg[bb * NJ + j];
            fst += sh_sst[bb * NJ + j];
            fmg = fmaxf(fmg, sh_mgA[bb * NJ + j]);
        }
        #pragma unroll
        for (int off = 4; off > 0; off >>= 1) {
            fsg += __shfl_down(fsg, off);
            fst += __shfl_down(fst, off);
            fmg = fmaxf(fmg, __shfl_down(fmg, off));
        }
        if (sub == 0) {
            const bool cond = (fmg == 1.0f);
            cond_sh[j] = cond ? 1.f : 0.f;
            const float inv_bhw = 1.f / (float)(NB * HW);
            msum_sh[j] = cond ? (fsg * inv_bhw) : ((fsg + fst) * inv_bhw);
        }
    }
    __syncthreads();

    // Stage 3: per-sample top-k on wave 0 (one thread per b), LDS-resident.
    if (tid < NB) {
        float lm[NJ];
        const float inv_hw = 1.f / (float)HW;
        #pragma unroll
        for (int j = 0; j < NJ; ++j) {
            const float fsg = sh_ssg[tid * NJ + j];
            const float fst = sh_sst[tid * NJ + j];
            const float v = (cond_sh[j] != 0.f) ? fsg : (fsg + fst);
            lm[j] = 0.5f * v * inv_hw;
        }
        float tk = 0.f;
        for (int k = 0; k < TOPK_K; ++k) {
            int mi = 0;
            float mv = lm[0];
            #pragma unroll
            for (int j = 1; j < NJ; ++j) {
                if (lm[j] > mv) { mv = lm[j]; mi = j; }
            }
            tk += mv;
            #pragma unroll
            for (int j = 0; j < NJ; ++j) {
                if (j == mi) lm[j] = -INFINITY;
            }
        }
        #pragma unroll
        for (int off = 32; off > 0; off >>= 1) tk += __shfl_down(tk, off);

        if (tid == 0) {
            const float ohkm = tk / (float)(TOPK_K * NB);
            float mse = 0.f;
            for (int j = 0; j < NJ; ++j) mse += msum_sh[j];
            const float enj = (float)(*enj_p);
            out[0] = ohkm;
            out[1] = mse / enj;
            out[2] = ohkm + mse;
        }
    }
}

extern "C" void kernel_launch(void* const* d_in, const int* in_sizes, int n_in,
                              void* d_out, int out_size, void* d_ws, size_t ws_size,
                              hipStream_t stream) {
    const float* output_s = (const float*)d_in[0];
    const float* output_t = (const float*)d_in[1];
    const float* target   = (const float*)d_in[2];
    const float* tweight  = (const float*)d_in[3];
    const int*   enj      = (const int*)d_in[4];
    float* out = (float*)d_out;
    float* ws  = (float*)d_ws;  // [counter(16B)] + 3 * NSEG * NBJ floats

    // zero only the 4-byte last-block counter (workspace is poisoned each run)
    hipMemsetAsync(d_ws, 0, 4, stream);
    fused_kernel<<<NBLOCKS, BLK, 0, stream>>>(output_s, output_t, target,
                                              tweight, enj, out, ws);
}

// Round 4
// 148.145 us; speedup vs baseline: 2.0190x; 1.0929x over previous
//
#include <hip/hip_runtime.h>
#include <math.h>

// Problem constants (from reference): B=64, J=17, H=W=96 -> HW=9216, TOPK=8
#define NB 64
#define NJ 17
#define HW 9216
#define NBJ (NB * NJ)              // 1088
#define TOPK_K 8
#define NSEG 3
#define SEG_F4 (HW / 4 / NSEG)     // 768 float4 per segment
#define BLK 256                    // threads per block (4 waves)
#define F4_PER_THR (SEG_F4 / BLK)  // 3 float4 per tensor per thread
#define NBLOCKS (NBJ * NSEG)       // 3264 streaming blocks; +1 spinner
#define NCNT 32                    // striped completion counters
#define CNT_STRIDE 32              // floats between counters (128 B lines)
#define WS_OFF 1024                // counter region: 1024 floats (4 KB)

// Round-2 lesson: __threadfence() -> buffer_wbl2+buffer_inv per block ->
// L2 thrash (10x). Round-3 lesson: fetch_add WITH return on one contended
// line -> every wave-0 stalls on a serialized RMW queue (+36 us).
// This round: fire-and-forget publication (sc1 stores, vmcnt(0) for order,
// NO-RETURN striped atomic adds) + a dedicated spinner block that polls the
// 32 counters and runs the final reduction. Streaming blocks never wait on
// contended memory.
__global__ __launch_bounds__(BLK) void fused_kernel(
    const float* __restrict__ s,
    const float* __restrict__ t,
    const float* __restrict__ g,
    const float* __restrict__ w,
    const int* __restrict__ enj_p,
    float* __restrict__ out,
    float* __restrict__ ws_raw)
{
    unsigned int* cnt = (unsigned int*)ws_raw;   // 32 counters, stride 32
    float* ws = ws_raw + WS_OFF;                 // [metric][seg][bj]

    __shared__ float sh_ssg[NBJ];
    __shared__ float sh_sst[NBJ];
    __shared__ float sh_mgA[NBJ];
    __shared__ float cond_sh[NJ];
    __shared__ float msum_sh[NJ];

    if (blockIdx.x < NBLOCKS) {
        // ---------------- streaming block ----------------
        const int bj  = blockIdx.x / NSEG;
        const int seg = blockIdx.x % NSEG;
        const size_t base4 = (size_t)bj * (HW / 4) + (size_t)seg * SEG_F4;
        const float4* __restrict__ s4 = (const float4*)s + base4;
        const float4* __restrict__ t4 = (const float4*)t + base4;
        const float4* __restrict__ g4 = (const float4*)g + base4;

        float4 a[F4_PER_THR], b[F4_PER_THR], c[F4_PER_THR];
        #pragma unroll
        for (int k = 0; k < F4_PER_THR; ++k) a[k] = s4[threadIdx.x + k * BLK];
        #pragma unroll
        for (int k = 0; k < F4_PER_THR; ++k) b[k] = t4[threadIdx.x + k * BLK];
        #pragma unroll
        for (int k = 0; k < F4_PER_THR; ++k) c[k] = g4[threadIdx.x + k * BLK];

        float ssg = 0.f, sst = 0.f, mg = -INFINITY;

        #define ACCUM(av, bv, cv)                                \
            {                                                    \
                float d1 = (av) - (cv), d2 = (av) - (bv);        \
                ssg += d1 * d1; sst += d2 * d2;                  \
                mg = fmaxf(mg, (cv));                            \
            }

        #pragma unroll
        for (int k = 0; k < F4_PER_THR; ++k) {
            ACCUM(a[k].x, b[k].x, c[k].x)
            ACCUM(a[k].y, b[k].y, c[k].y)
            ACCUM(a[k].z, b[k].z, c[k].z)
            ACCUM(a[k].w, b[k].w, c[k].w)
        }
        #undef ACCUM

        // wave64 butterfly reduction
        #pragma unroll
        for (int off = 32; off > 0; off >>= 1) {
            ssg += __shfl_down(ssg, off);
            sst += __shfl_down(sst, off);
            mg = fmaxf(mg, __shfl_down(mg, off));
        }

        __shared__ float sh_sg[4], sh_st[4], sh_mg4[4];
        const int wave = threadIdx.x >> 6;
        const int lane = threadIdx.x & 63;
        if (lane == 0) { sh_sg[wave] = ssg; sh_st[wave] = sst; sh_mg4[wave] = mg; }
        __syncthreads();

        if (threadIdx.x == 0) {
            const float fsg = (sh_sg[0] + sh_sg[1]) + (sh_sg[2] + sh_sg[3]);
            const float fst = (sh_st[0] + sh_st[1]) + (sh_st[2] + sh_st[3]);
            const float fmg = fmaxf(fmaxf(sh_mg4[0], sh_mg4[1]),
                                    fmaxf(sh_mg4[2], sh_mg4[3]));
            // publish partials at agent scope (sc1 -> IC, die-coherent)
            __hip_atomic_store(&ws[(0 * NSEG + seg) * NBJ + bj], fsg,
                               __ATOMIC_RELAXED, __HIP_MEMORY_SCOPE_AGENT);
            __hip_atomic_store(&ws[(1 * NSEG + seg) * NBJ + bj], fst,
                               __ATOMIC_RELAXED, __HIP_MEMORY_SCOPE_AGENT);
            __hip_atomic_store(&ws[(2 * NSEG + seg) * NBJ + bj], fmg,
                               __ATOMIC_RELAXED, __HIP_MEMORY_SCOPE_AGENT);
            // order: data stores acked at coherence point before counter add
            asm volatile("s_waitcnt vmcnt(0)" ::: "memory");
            // fire-and-forget (no return -> no stall), striped over 32 lines
            unsigned int* my_cnt = cnt + (blockIdx.x & (NCNT - 1)) * CNT_STRIDE;
            __hip_atomic_fetch_add(my_cnt, 1u, __ATOMIC_RELAXED,
                                   __HIP_MEMORY_SCOPE_AGENT);
        }
        return;  // streaming blocks retire immediately
    }

    // ---------------- spinner / finalizer block ----------------
    const int tid = threadIdx.x;
    if (tid == 0) {
        unsigned total;
        do {
            total = 0;
            #pragma unroll
            for (int i = 0; i < NCNT; ++i)
                total += __hip_atomic_load(cnt + i * CNT_STRIDE,
                                           __ATOMIC_RELAXED,
                                           __HIP_MEMORY_SCOPE_AGENT);
            if (total < (unsigned)NBLOCKS) __builtin_amdgcn_s_sleep(8);
        } while (total < (unsigned)NBLOCKS);
    }
    __syncthreads();

    // Stage 1: fold segments (agent-scope loads: fresh from IC), apply w^2.
    for (int i = tid; i < NBJ; i += BLK) {
        float fsg = 0.f, fst = 0.f, fmg = -INFINITY;
        #pragma unroll
        for (int sg2 = 0; sg2 < NSEG; ++sg2) {
            fsg += __hip_atomic_load(&ws[(0 * NSEG + sg2) * NBJ + i],
                                     __ATOMIC_RELAXED, __HIP_MEMORY_SCOPE_AGENT);
            fst += __hip_atomic_load(&ws[(1 * NSEG + sg2) * NBJ + i],
                                     __ATOMIC_RELAXED, __HIP_MEMORY_SCOPE_AGENT);
            fmg = fmaxf(fmg,
                  __hip_atomic_load(&ws[(2 * NSEG + sg2) * NBJ + i],
                                     __ATOMIC_RELAXED, __HIP_MEMORY_SCOPE_AGENT));
        }
        const float wv = w[i];
        const float w2 = wv * wv;
        sh_ssg[i] = fsg * w2;
        sh_sst[i] = fst * w2;
        sh_mgA[i] = fmg;
    }
    __syncthreads();

    // Stage 2: per-joint cond + mse. 8 lanes per joint (17*8 = 136 threads),
    // intra-8-lane shuffle tree (groups lane-aligned within wave64).
    if (tid < NJ * 8) {
        const int j = tid >> 3;
        const int sub = tid & 7;
        float fsg = 0.f, fst = 0.f, fmg = -INFINITY;
        for (int bb = sub; bb < NB; bb += 8) {
            fsg += sh_ssg[bb * NJ + j];
            fst += sh_sst[bb * NJ + j];
            fmg = fmaxf(fmg, sh_mgA[bb * NJ + j]);
        }
        #pragma unroll
        for (int off = 4; off > 0; off >>= 1) {
            fsg += __shfl_down(fsg, off);
            fst += __shfl_down(fst, off);
            fmg = fmaxf(fmg, __shfl_down(fmg, off));
        }
        if (sub == 0) {
            const bool cond = (fmg == 1.0f);
            cond_sh[j] = cond ? 1.f : 0.f;
            const float inv_bhw = 1.f / (float)(NB * HW);
            msum_sh[j] = cond ? (fsg * inv_bhw) : ((fsg + fst) * inv_bhw);
        }
    }
    __syncthreads();

    // Stage 3: per-sample top-k on wave 0 (one thread per b), LDS-resident.
    if (tid < NB) {
        float lm[NJ];
        const float inv_hw = 1.f / (float)HW;
        #pragma unroll
        for (int j = 0; j < NJ; ++j) {
            const float fsg = sh_ssg[tid * NJ + j];
            const float fst = sh_sst[tid * NJ + j];
            const float v = (cond_sh[j] != 0.f) ? fsg : (fsg + fst);
            lm[j] = 0.5f * v * inv_hw;
        }
        float tk = 0.f;
        for (int k = 0; k < TOPK_K; ++k) {
            int mi = 0;
            float mv = lm[0];
            #pragma unroll
            for (int j = 1; j < NJ; ++j) {
                if (lm[j] > mv) { mv = lm[j]; mi = j; }
            }
            tk += mv;
            #pragma unroll
            for (int j = 0; j < NJ; ++j) {
                if (j == mi) lm[j] = -INFINITY;
            }
        }
        #pragma unroll
        for (int off = 32; off > 0; off >>= 1) tk += __shfl_down(tk, off);

        if (tid == 0) {
            const float ohkm = tk / (float)(TOPK_K * NB);
            float mse = 0.f;
            for (int j = 0; j < NJ; ++j) mse += msum_sh[j];
            const float enj = (float)(*enj_p);
            out[0] = ohkm;
            out[1] = mse / enj;
            out[2] = ohkm + mse;
        }
    }
}

extern "C" void kernel_launch(void* const* d_in, const int* in_sizes, int n_in,
                              void* d_out, int out_size, void* d_ws, size_t ws_size,
                              hipStream_t stream) {
    const float* output_s = (const float*)d_in[0];
    const float* output_t = (const float*)d_in[1];
    const float* target   = (const float*)d_in[2];
    const float* tweight  = (const float*)d_in[3];
    const int*   enj      = (const int*)d_in[4];
    float* out = (float*)d_out;
    float* ws  = (float*)d_ws;  // [32 counters, 4 KB] + 3*NSEG*NBJ floats

    // zero the striped counter region (workspace is poisoned each run)
    hipMemsetAsync(d_ws, 0, WS_OFF * sizeof(float), stream);
    fused_kernel<<<NBLOCKS + 1, BLK, 0, stream>>>(output_s, output_t, target,
                                                  tweight, enj, out, ws);
}